// Round 16
// baseline (436.096 us; speedup 1.0000x reference)
//
#include <hip/hip_runtime.h>
#include <hip/hip_bf16.h>

#define TT 4096
#define SS 4096
#define DD 128
#define HUGEV 1e30f

#define RR 8                    // rows per lane
#define KK 8                    // cols per sub-step
#define BH (64 * RR)            // band height = 512
#define NBANDS 8                // 4 forward + 4 backward (mirrored)
#define NCHUNK (SS / KK)        // 512 col-chunks per band
#define NSIG 576                // sigma slots (tc + lane: 0..574, padded)
#define NSIGA 584               // allocated slots (pad tiles)
#define NG 72                   // 72 groups x 8 steps = 576 super-steps
#define SPIN_MAX (1 << 24)      // deadlock escape; legit waits << this

// DPP wave_shr:1 — lane l receives lane l-1's src; lane 0 receives `old`.
__device__ __forceinline__ float shr1(float oldv, float src) {
  return __uint_as_float((unsigned)__builtin_amdgcn_update_dpp(
      (int)__float_as_uint(oldv), (int)__float_as_uint(src),
      0x138 /*wave_shr:1*/, 0xf, 0xf, false));
}

// ---------------- init: zero progress flags (graph replay!) ----------------
__global__ __launch_bounds__(64) void dtw_init(int* __restrict__ progress) {
  __hip_atomic_store(progress + threadIdx.x, 0, __ATOMIC_RELAXED,
                     __HIP_MEMORY_SCOPE_AGENT);
}

// ---------------- row norms ----------------
__global__ __launch_bounds__(256) void dtw_norms(const float* __restrict__ ref,
                                                 const float* __restrict__ tgt,
                                                 float* __restrict__ r2,
                                                 float* __restrict__ t2) {
  int i = blockIdx.x * 256 + threadIdx.x;
  const float* p = (i < TT) ? (ref + (size_t)i * DD) : (tgt + (size_t)(i - TT) * DD);
  float s = 0.f;
#pragma unroll
  for (int k = 0; k < DD; k += 4) {
    float4 v = *(const float4*)(p + k);
    s = fmaf(v.x, v.x, s); s = fmaf(v.y, v.y, s);
    s = fmaf(v.z, v.z, s); s = fmaf(v.w, v.w, s);
  }
  if (i < TT) r2[i] = s; else t2[i - TT] = s;
}

// ---------------- dist -> skewed COALESCED tile layout, bf16 ----------------
// Forward half (i<2048): b=i>>9, lane=(i>>3)&63, r=i&7, tc=j>>3, k=j&7.
// Backward half (i>=2048): mirrored i'=4095-i, j'=4095-j, band 4+(i'>>9).
// ushort index = (((b*NSIGA + tc+lane)*8 + r)*64 + lane)*8 + k.
__global__ __launch_bounds__(256) void dtw_dist(const float* __restrict__ ref,
                                                const float* __restrict__ tgt,
                                                const float* __restrict__ r2,
                                                const float* __restrict__ t2,
                                                unsigned short* __restrict__ dist) {
  __shared__ float As[32][68];
  __shared__ float Bs[32][68];
  const int tid = threadIdx.x;
  const int tx = tid & 15, ty = tid >> 4;
  const int i0 = blockIdx.y * 64, j0 = blockIdx.x * 64;
  const int lrow = tid >> 3;
  const int lk = (tid & 7) << 2;
  const float* ap = ref + (size_t)(i0 + lrow) * DD + lk;
  const float* bp = tgt + (size_t)(j0 + lrow) * DD + lk;
  float acc[4][4] = {};
  for (int k0 = 0; k0 < DD; k0 += 32) {
    float4 a0 = *(const float4*)(ap + k0);
    float4 a1 = *(const float4*)(ap + k0 + 32 * DD);
    float4 b0 = *(const float4*)(bp + k0);
    float4 b1 = *(const float4*)(bp + k0 + 32 * DD);
    __syncthreads();
    As[lk + 0][lrow] = a0.x; As[lk + 1][lrow] = a0.y; As[lk + 2][lrow] = a0.z; As[lk + 3][lrow] = a0.w;
    As[lk + 0][lrow + 32] = a1.x; As[lk + 1][lrow + 32] = a1.y; As[lk + 2][lrow + 32] = a1.z; As[lk + 3][lrow + 32] = a1.w;
    Bs[lk + 0][lrow] = b0.x; Bs[lk + 1][lrow] = b0.y; Bs[lk + 2][lrow] = b0.z; Bs[lk + 3][lrow] = b0.w;
    Bs[lk + 0][lrow + 32] = b1.x; Bs[lk + 1][lrow + 32] = b1.y; Bs[lk + 2][lrow + 32] = b1.z; Bs[lk + 3][lrow + 32] = b1.w;
    __syncthreads();
#pragma unroll
    for (int k = 0; k < 32; ++k) {
      float4 av = *(const float4*)&As[k][ty << 2];
      float4 bv = *(const float4*)&Bs[k][tx << 2];
      float aa[4] = {av.x, av.y, av.z, av.w};
      float bb[4] = {bv.x, bv.y, bv.z, bv.w};
#pragma unroll
      for (int r = 0; r < 4; ++r)
#pragma unroll
        for (int c = 0; c < 4; ++c) acc[r][c] = fmaf(aa[r], bb[c], acc[r][c]);
    }
  }
  const bool fwd = (i0 < TT / 2);
#pragma unroll
  for (int r = 0; r < 4; ++r) {
    const int i = i0 + (ty << 2) + r;
    const float ri = r2[i];
    unsigned short oo[4];
#pragma unroll
    for (int c = 0; c < 4; ++c) {
      int j = j0 + (tx << 2) + c;
      float d2 = ri + t2[j] - 2.0f * acc[r][c];
      float dd = sqrtf(fmaxf(d2, 0.f));
      unsigned bits = __float_as_uint(dd);
      oo[c] = (unsigned short)((bits + 0x7FFFu + ((bits >> 16) & 1u)) >> 16);
    }
    const int jj = j0 + (tx << 2);
    if (fwd) {
      ushort4 ov; ov.x = oo[0]; ov.y = oo[1]; ov.z = oo[2]; ov.w = oo[3];
      const int bnd = i >> 9, ln = (i >> 3) & 63, rr = i & 7;
      const int tc = jj >> 3, kk0 = jj & 7;
      const size_t idx =
          ((((size_t)bnd * NSIGA + tc + ln) * 8 + rr) * 64 + ln) * 8 + kk0;
      *reinterpret_cast<ushort4*>(dist + idx) = ov;
    } else {
      const int ip = (TT - 1) - i;                  // mirrored row
      const int bnd = 4 + (ip >> 9), ln = (ip >> 3) & 63, rr = ip & 7;
      const int jb = (SS - 4) - jj;                 // mirrored col base (c=3)
      const int tc = jb >> 3, kk0 = jb & 7;
      ushort4 ov; ov.x = oo[3]; ov.y = oo[2]; ov.z = oo[1]; ov.w = oo[0];
      const size_t idx =
          ((((size_t)bnd * NSIGA + tc + ln) * 8 + rr) * 64 + ln) * 8 + kk0;
      *reinterpret_cast<ushort4*>(dist + idx) = ov;
    }
  }
}

// ---------------- banded wavefront DP: bidirectional, register ring ----------
// Rolling-scalar DP body (low register pressure -> ring stays in arch VGPRs,
// no AGPR round-trips) + waves_per_eu(1) to give regalloc the full budget.

#define ACQ_LDS(P) __hip_atomic_load((P), __ATOMIC_ACQUIRE, __HIP_MEMORY_SCOPE_WORKGROUP)
#define RLX_LDS(P, V) __hip_atomic_store((P), (V), __ATOMIC_RELAXED, __HIP_MEMORY_SCOPE_WORKGROUP)
#define CBAR() asm volatile("" ::: "memory")

#define LOAD8(QS, TBS)                                                         \
  asm volatile("global_load_dwordx4 %0, %1, %2"             : "=v"(QS[0]) : "v"(vo),  "s"(TBS)); \
  asm volatile("global_load_dwordx4 %0, %1, %2 offset:1024" : "=v"(QS[1]) : "v"(vo),  "s"(TBS)); \
  asm volatile("global_load_dwordx4 %0, %1, %2 offset:2048" : "=v"(QS[2]) : "v"(vo),  "s"(TBS)); \
  asm volatile("global_load_dwordx4 %0, %1, %2 offset:3072" : "=v"(QS[3]) : "v"(vo),  "s"(TBS)); \
  asm volatile("global_load_dwordx4 %0, %1, %2"             : "=v"(QS[4]) : "v"(vo2), "s"(TBS)); \
  asm volatile("global_load_dwordx4 %0, %1, %2 offset:1024" : "=v"(QS[5]) : "v"(vo2), "s"(TBS)); \
  asm volatile("global_load_dwordx4 %0, %1, %2 offset:2048" : "=v"(QS[6]) : "v"(vo2), "s"(TBS)); \
  asm volatile("global_load_dwordx4 %0, %1, %2 offset:3072" : "=v"(QS[7]) : "v"(vo2), "s"(TBS));

// fence: tiles sigma, sigma+1 landed (tiles sigma+2, sigma+3 stay in flight)
#define DPFENCE()                                                              \
  asm volatile("s_waitcnt vmcnt(16)" ::: "memory");                            \
  __builtin_amdgcn_sched_barrier(0);

#define DPSTEP(G, S, QS)                                                       \
  {                                                                            \
    const int sigma = 8 * (G) + (S);                                           \
    float4 ub0 = *(const float4*)&ubuf[ubase + 8 * (((S) + 1) & 7)];           \
    float4 ub1 = *(const float4*)&ubuf[ubase + 8 * (((S) + 1) & 7) + 4];       \
    float uba_s[8] = {ub0.x, ub0.y, ub0.z, ub0.w, ub1.x, ub1.y, ub1.z, ub1.w}; \
    float bot[KK];                                                             \
    float ul = ul_top;                                                         \
    _Pragma("unroll")                                                          \
    for (int k = 0; k < KK; ++k) {                                             \
      const float uin = u[k];                                                  \
      float up = uin, ulr = ul;                                                \
      _Pragma("unroll")                                                        \
      for (int r = 0; r < RR; ++r) {                                           \
        unsigned w = ((k >> 1) == 0) ? QS[r].x                                 \
                   : ((k >> 1) == 1) ? QS[r].y                                 \
                   : ((k >> 1) == 2) ? QS[r].z : QS[r].w;                      \
        float dv = (k & 1) ? __uint_as_float(w & 0xffff0000u)                  \
                           : __uint_as_float(w << 16);                         \
        float diag = left[r];                                                  \
        float nv = dv + fminf(fminf(up, ulr), left[r]);                        \
        left[r] = nv; ulr = diag; up = nv;                                     \
      }                                                                        \
      bot[k] = up;                                                             \
      u[k] = shr1(uba_s[k], up);                                               \
      ul = uin;                                                                \
    }                                                                          \
    ul_top = ul;                                                               \
    /* re-issue this slot for tile sigma+4 (uniform SGPR base, padded alloc) */\
    {                                                                          \
      const unsigned short* tbs = tb + (size_t)(sigma + 4) * 4096;             \
      LOAD8(QS, tbs)                                                           \
    }                                                                          \
    if (sigma >= 63 && lane == 63) {                                           \
      const int c63 = sigma - 63;                                              \
      float* orp = &outring[c63 & 63][0];                                      \
      *(float2*)(orp + 0) = make_float2(bot[0], bot[1]);                       \
      *(float2*)(orp + 2) = make_float2(bot[2], bot[3]);                       \
      *(float2*)(orp + 4) = make_float2(bot[4], bot[5]);                       \
      *(float2*)(orp + 6) = make_float2(bot[6], bot[7]);                       \
      CBAR();                                                                  \
      if ((S) == 6 && sigma >= 70) RLX_LDS(&sh_out, c63 + 1);                  \
    }                                                                          \
  }

__global__ __launch_bounds__(128, 1)
__attribute__((amdgpu_waves_per_eu(1)))
void dtw_dp(const unsigned short* __restrict__ dist,
            float* __restrict__ brow,
            int* __restrict__ progress) {
  const int tid = threadIdx.x;
  const int lane = tid & 63;
  const int wid = tid >> 6;
  const int b = blockIdx.x;
  const int sb = b & 3;          // band index within its side

  __shared__ __align__(16) float ubuf[128];
  __shared__ __align__(16) float outring[64][KK];
  __shared__ int sh_out, sh_pubc, sh_ubc, sh_gdone;

  if (tid == 0) { sh_out = 0; sh_pubc = 0; sh_ubc = 0; sh_gdone = 0; }
  ubuf[tid] = HUGEV;
  __syncthreads();

  const unsigned short* tb = dist + (size_t)b * NSIGA * 4096;

  if (wid == 1) {
    // ================= aux wave: boundary-in + publish-out ==================
    int ubg = (sb > 0) ? 0 : 64;
    int pubg = 0;                          // ALL bands publish (combine needs 3,7)
    int out_c = 0, gdone_c = 0, idle = 0;
    while (ubg < 64 || pubg < 64) {
      bool did = false;
      if (ubg < 64) {
        if (gdone_c < ubg - 1) gdone_c = ACQ_LDS(&sh_gdone);
        if (gdone_c >= ubg - 1) {
          int pr = __hip_atomic_load(progress + b - 1, __ATOMIC_RELAXED,
                                     __HIP_MEMORY_SCOPE_AGENT);
          if (pr >= ubg + 1) {
            float v = __hip_atomic_load(brow + (size_t)(b - 1) * SS + 64 * ubg + lane,
                                        __ATOMIC_RELAXED, __HIP_MEMORY_SCOPE_AGENT);
            asm volatile("s_waitcnt vmcnt(0)" ::: "memory");
            ubuf[((ubg & 1) << 6) + lane] = v;
            CBAR();
            if (lane == 0) RLX_LDS(&sh_ubc, ubg + 1);
            ubg++; did = true;
          }
        }
      }
      if (pubg < 64) {
        if (out_c < 8 * (pubg + 1)) out_c = ACQ_LDS(&sh_out);
        if (out_c >= 8 * (pubg + 1)) {
          float v = outring[((pubg << 3) + (lane >> 3)) & 63][lane & 7];
          __hip_atomic_store(brow + (size_t)b * SS + 64 * pubg + lane, v,
                             __ATOMIC_RELAXED, __HIP_MEMORY_SCOPE_AGENT);
          asm volatile("s_waitcnt vmcnt(0)" ::: "memory");
          if (lane == 0) {
            __hip_atomic_store(progress + b, pubg + 1, __ATOMIC_RELAXED,
                               __HIP_MEMORY_SCOPE_AGENT);
            RLX_LDS(&sh_pubc, (pubg + 1) << 3);
          }
          pubg++; did = true;
        }
      }
      if (!did) {
        __builtin_amdgcn_s_sleep(2);
        if (++idle > SPIN_MAX) break;
      } else idle = 0;
    }
  } else {
    // ================= compute wave =================
    __builtin_amdgcn_s_setprio(1);
    float left[RR], u[KK], ul_top;
#pragma unroll
    for (int r = 0; r < RR; ++r) left[r] = HUGEV;
#pragma unroll
    for (int k = 0; k < KK; ++k) u[k] = HUGEV;
    ul_top = (sb == 0 && lane == 0) ? 0.f : HUGEV;   // origin seed per side

    int pubc = 0, ubc = 0;
    uint4 qA[8], qB[8], qC[8], qD[8];

    const unsigned vo = (unsigned)lane * 16u;
    const unsigned vo2 = vo + 4096u;

    // prologue: issue tiles 0..3 into the 4-slot ring (32 loads in flight)
    { const unsigned short* tbs = tb;                    LOAD8(qA, tbs) }
    { const unsigned short* tbs = tb + (size_t)1 * 4096; LOAD8(qB, tbs) }
    { const unsigned short* tbs = tb + (size_t)2 * 4096; LOAD8(qC, tbs) }
    { const unsigned short* tbs = tb + (size_t)3 * 4096; LOAD8(qD, tbs) }

    for (int g = 0; g < NG; ++g) {
      const int ubase = (g & 1) << 6;
      if (sb > 0 && g < 64 && ubc < g + 1) {
        int _gd = 0;
        do { ubc = ACQ_LDS(&sh_ubc); } while (ubc < g + 1 && ++_gd < SPIN_MAX);
      }
      { // outring space for this group
        const int need = 8 * g - 119;
        if (need > 0 && pubc < need) {
          int _gd = 0;
          do { pubc = ACQ_LDS(&sh_pubc); } while (pubc < need && ++_gd < SPIN_MAX);
        }
      }
      { // group head: lane-0 u fix-up from ubuf
        float4 h0 = *(const float4*)&ubuf[ubase];
        float4 h1 = *(const float4*)&ubuf[ubase + 4];
        float hh[8] = {h0.x, h0.y, h0.z, h0.w, h1.x, h1.y, h1.z, h1.w};
#pragma unroll
        for (int k = 0; k < KK; ++k) u[k] = (lane == 0) ? hh[k] : u[k];
      }
      DPFENCE()
      DPSTEP(g, 0, qA)
      DPSTEP(g, 1, qB)
      DPFENCE()
      DPSTEP(g, 2, qC)
      DPSTEP(g, 3, qD)
      DPFENCE()
      DPSTEP(g, 4, qA)
      DPSTEP(g, 5, qB)
      DPFENCE()
      DPSTEP(g, 6, qC)
      DPSTEP(g, 7, qD)
      if (lane == 0) RLX_LDS(&sh_gdone, g + 1);
    }
    asm volatile("s_waitcnt vmcnt(0)" ::: "memory");
  }
}

// ---------------- combine: min_j ( F[2047][j] + min(B[2048][j], B[2048][j+1]) )
__global__ __launch_bounds__(256) void dtw_combine(const float* __restrict__ brow,
                                                   float* __restrict__ out) {
  const float* browF = brow + (size_t)3 * SS;
  const float* browB = brow + (size_t)7 * SS;
  __shared__ float red[256];
  const int t = threadIdx.x;
  float m = HUGEV;
  for (int j = t; j < SS; j += 256) {
    float b1 = browB[(SS - 1) - j];
    float b2 = (j < SS - 1) ? browB[(SS - 2) - j] : HUGEV;
    m = fminf(m, browF[j] + fminf(b1, b2));
  }
  red[t] = m;
  __syncthreads();
  for (int s = 128; s > 0; s >>= 1) {
    if (t < s) red[t] = fminf(red[t], red[t + s]);
    __syncthreads();
  }
  if (t == 0) out[0] = red[0];
}

extern "C" void kernel_launch(void* const* d_in, const int* in_sizes, int n_in,
                              void* d_out, int out_size, void* d_ws, size_t ws_size,
                              hipStream_t stream) {
  const float* ref = (const float*)d_in[0];
  const float* tgt = (const float*)d_in[1];
  float* out = (float*)d_out;
  char* ws = (char*)d_ws;
  unsigned short* dist = (unsigned short*)ws;       // skewed tiles (padded): 38.3 MB
  size_t off = (size_t)NBANDS * NSIGA * 4096 * 2;
  float* brow = (float*)(ws + off);      off += (size_t)64 * SS * 4;
  int* progress = (int*)(ws + off);      off += 1024;
  float* r2 = (float*)(ws + off);        off += (size_t)TT * 4;
  float* t2 = (float*)(ws + off);

  dtw_init<<<1, 64, 0, stream>>>(progress);
  dtw_norms<<<(TT + SS) / 256, 256, 0, stream>>>(ref, tgt, r2, t2);
  dtw_dist<<<dim3(SS / 64, TT / 64), 256, 0, stream>>>(ref, tgt, r2, t2, dist);
  dtw_dp<<<NBANDS, 128, 0, stream>>>(dist, brow, progress);
  dtw_combine<<<1, 256, 0, stream>>>(brow, out);
}

// Round 17
// 430.473 us; speedup vs baseline: 1.0131x; 1.0131x over previous
//
#include <hip/hip_runtime.h>
#include <hip/hip_bf16.h>

#define TT 4096
#define SS 4096
#define DD 128
#define HUGEV 1e30f

#define RR 8                    // rows per lane
#define KK 8                    // cols per sub-step
#define BH (64 * RR)            // band height = 512
#define NBANDS 8                // 4 forward + 4 backward (mirrored)
#define NCHUNK (SS / KK)        // 512 col-chunks per band
#define NSIG 576                // sigma slots (tc + lane: 0..574, padded)
#define NSIGA 584               // allocated slots (pad tiles)
#define NG 72                   // 72 groups x 8 steps = 576 super-steps
#define SPIN_MAX (1 << 24)      // deadlock escape; legit waits << this

// DPP wave_shr:1 — lane l receives lane l-1's src; lane 0 receives `old`.
__device__ __forceinline__ float shr1(float oldv, float src) {
  return __uint_as_float((unsigned)__builtin_amdgcn_update_dpp(
      (int)__float_as_uint(oldv), (int)__float_as_uint(src),
      0x138 /*wave_shr:1*/, 0xf, 0xf, false));
}

// ---------------- row norms + progress-flag init (fused; graph replay!) -----
__global__ __launch_bounds__(256) void dtw_norms(const float* __restrict__ ref,
                                                 const float* __restrict__ tgt,
                                                 float* __restrict__ r2,
                                                 float* __restrict__ t2,
                                                 int* __restrict__ progress) {
  if (blockIdx.x == 0 && threadIdx.x < 64)
    __hip_atomic_store(progress + threadIdx.x, 0, __ATOMIC_RELAXED,
                       __HIP_MEMORY_SCOPE_AGENT);
  int i = blockIdx.x * 256 + threadIdx.x;
  const float* p = (i < TT) ? (ref + (size_t)i * DD) : (tgt + (size_t)(i - TT) * DD);
  float s = 0.f;
#pragma unroll
  for (int k = 0; k < DD; k += 4) {
    float4 v = *(const float4*)(p + k);
    s = fmaf(v.x, v.x, s); s = fmaf(v.y, v.y, s);
    s = fmaf(v.z, v.z, s); s = fmaf(v.w, v.w, s);
  }
  if (i < TT) r2[i] = s; else t2[i - TT] = s;
}

// ---------------- dist -> skewed COALESCED tile layout, bf16 ----------------
// Forward half (i<2048): b=i>>9, lane=(i>>3)&63, r=i&7, tc=j>>3, k=j&7.
// Backward half (i>=2048): mirrored i'=4095-i, j'=4095-j, band 4+(i'>>9).
// ushort index = (((b*NSIGA + tc+lane)*8 + r)*64 + lane)*8 + k.
__global__ __launch_bounds__(256) void dtw_dist(const float* __restrict__ ref,
                                                const float* __restrict__ tgt,
                                                const float* __restrict__ r2,
                                                const float* __restrict__ t2,
                                                unsigned short* __restrict__ dist) {
  __shared__ float As[32][68];
  __shared__ float Bs[32][68];
  const int tid = threadIdx.x;
  const int tx = tid & 15, ty = tid >> 4;
  const int i0 = blockIdx.y * 64, j0 = blockIdx.x * 64;
  const int lrow = tid >> 3;
  const int lk = (tid & 7) << 2;
  const float* ap = ref + (size_t)(i0 + lrow) * DD + lk;
  const float* bp = tgt + (size_t)(j0 + lrow) * DD + lk;
  float acc[4][4] = {};
  for (int k0 = 0; k0 < DD; k0 += 32) {
    float4 a0 = *(const float4*)(ap + k0);
    float4 a1 = *(const float4*)(ap + k0 + 32 * DD);
    float4 b0 = *(const float4*)(bp + k0);
    float4 b1 = *(const float4*)(bp + k0 + 32 * DD);
    __syncthreads();
    As[lk + 0][lrow] = a0.x; As[lk + 1][lrow] = a0.y; As[lk + 2][lrow] = a0.z; As[lk + 3][lrow] = a0.w;
    As[lk + 0][lrow + 32] = a1.x; As[lk + 1][lrow + 32] = a1.y; As[lk + 2][lrow + 32] = a1.z; As[lk + 3][lrow + 32] = a1.w;
    Bs[lk + 0][lrow] = b0.x; Bs[lk + 1][lrow] = b0.y; Bs[lk + 2][lrow] = b0.z; Bs[lk + 3][lrow] = b0.w;
    Bs[lk + 0][lrow + 32] = b1.x; Bs[lk + 1][lrow + 32] = b1.y; Bs[lk + 2][lrow + 32] = b1.z; Bs[lk + 3][lrow + 32] = b1.w;
    __syncthreads();
#pragma unroll
    for (int k = 0; k < 32; ++k) {
      float4 av = *(const float4*)&As[k][ty << 2];
      float4 bv = *(const float4*)&Bs[k][tx << 2];
      float aa[4] = {av.x, av.y, av.z, av.w};
      float bb[4] = {bv.x, bv.y, bv.z, bv.w};
#pragma unroll
      for (int r = 0; r < 4; ++r)
#pragma unroll
        for (int c = 0; c < 4; ++c) acc[r][c] = fmaf(aa[r], bb[c], acc[r][c]);
    }
  }
  const bool fwd = (i0 < TT / 2);
#pragma unroll
  for (int r = 0; r < 4; ++r) {
    const int i = i0 + (ty << 2) + r;
    const float ri = r2[i];
    unsigned short oo[4];
#pragma unroll
    for (int c = 0; c < 4; ++c) {
      int j = j0 + (tx << 2) + c;
      float d2 = ri + t2[j] - 2.0f * acc[r][c];
      float dd = sqrtf(fmaxf(d2, 0.f));
      unsigned bits = __float_as_uint(dd);
      oo[c] = (unsigned short)((bits + 0x7FFFu + ((bits >> 16) & 1u)) >> 16);
    }
    const int jj = j0 + (tx << 2);
    if (fwd) {
      ushort4 ov; ov.x = oo[0]; ov.y = oo[1]; ov.z = oo[2]; ov.w = oo[3];
      const int bnd = i >> 9, ln = (i >> 3) & 63, rr = i & 7;
      const int tc = jj >> 3, kk0 = jj & 7;
      const size_t idx =
          ((((size_t)bnd * NSIGA + tc + ln) * 8 + rr) * 64 + ln) * 8 + kk0;
      *reinterpret_cast<ushort4*>(dist + idx) = ov;
    } else {
      const int ip = (TT - 1) - i;                  // mirrored row
      const int bnd = 4 + (ip >> 9), ln = (ip >> 3) & 63, rr = ip & 7;
      const int jb = (SS - 4) - jj;                 // mirrored col base (c=3)
      const int tc = jb >> 3, kk0 = jb & 7;
      ushort4 ov; ov.x = oo[3]; ov.y = oo[2]; ov.z = oo[1]; ov.w = oo[0];
      const size_t idx =
          ((((size_t)bnd * NSIGA + tc + ln) * 8 + rr) * 64 + ln) * 8 + kk0;
      *reinterpret_cast<ushort4*>(dist + idx) = ov;
    }
  }
}

// ---------------- banded wavefront DP: bidirectional, register ring ----------
// R16 structure + (1) uba register double-buffer (no per-step LDS read on the
// critical path), (2) compiler memory barrier once per group instead of per
// step (wave-ordered DS completion covers data-before-flag).

#define ACQ_LDS(P) __hip_atomic_load((P), __ATOMIC_ACQUIRE, __HIP_MEMORY_SCOPE_WORKGROUP)
#define RLX_LDS(P, V) __hip_atomic_store((P), (V), __ATOMIC_RELAXED, __HIP_MEMORY_SCOPE_WORKGROUP)
#define CBAR() asm volatile("" ::: "memory")

#define LOAD8(QS, TBS)                                                         \
  asm volatile("global_load_dwordx4 %0, %1, %2"             : "=v"(QS[0]) : "v"(vo),  "s"(TBS)); \
  asm volatile("global_load_dwordx4 %0, %1, %2 offset:1024" : "=v"(QS[1]) : "v"(vo),  "s"(TBS)); \
  asm volatile("global_load_dwordx4 %0, %1, %2 offset:2048" : "=v"(QS[2]) : "v"(vo),  "s"(TBS)); \
  asm volatile("global_load_dwordx4 %0, %1, %2 offset:3072" : "=v"(QS[3]) : "v"(vo),  "s"(TBS)); \
  asm volatile("global_load_dwordx4 %0, %1, %2"             : "=v"(QS[4]) : "v"(vo2), "s"(TBS)); \
  asm volatile("global_load_dwordx4 %0, %1, %2 offset:1024" : "=v"(QS[5]) : "v"(vo2), "s"(TBS)); \
  asm volatile("global_load_dwordx4 %0, %1, %2 offset:2048" : "=v"(QS[6]) : "v"(vo2), "s"(TBS)); \
  asm volatile("global_load_dwordx4 %0, %1, %2 offset:3072" : "=v"(QS[7]) : "v"(vo2), "s"(TBS));

// fence: tiles sigma, sigma+1 landed (tiles sigma+2, sigma+3 stay in flight)
#define DPFENCE()                                                              \
  asm volatile("s_waitcnt vmcnt(16)" ::: "memory");                            \
  __builtin_amdgcn_sched_barrier(0);

#define DPSTEP(G, S, QS, UBA, UBN)                                             \
  {                                                                            \
    const int sigma = 8 * (G) + (S);                                           \
    float uba_s[8] = {UBA[0].x, UBA[0].y, UBA[0].z, UBA[0].w,                  \
                      UBA[1].x, UBA[1].y, UBA[1].z, UBA[1].w};                 \
    { /* prefetch next step's uba (slots 0,1 at S=6,7 are dummies) */          \
      const float4* up4 = (const float4*)&ubuf[ubase + 8 * (((S) + 2) & 7)];   \
      UBN[0] = up4[0]; UBN[1] = up4[1];                                        \
    }                                                                          \
    float bot[KK];                                                             \
    float ul = ul_top;                                                         \
    _Pragma("unroll")                                                          \
    for (int k = 0; k < KK; ++k) {                                             \
      const float uin = u[k];                                                  \
      float up = uin, ulr = ul;                                                \
      _Pragma("unroll")                                                        \
      for (int r = 0; r < RR; ++r) {                                           \
        unsigned w = ((k >> 1) == 0) ? QS[r].x                                 \
                   : ((k >> 1) == 1) ? QS[r].y                                 \
                   : ((k >> 1) == 2) ? QS[r].z : QS[r].w;                      \
        float dv = (k & 1) ? __uint_as_float(w & 0xffff0000u)                  \
                           : __uint_as_float(w << 16);                         \
        float diag = left[r];                                                  \
        float nv = dv + fminf(fminf(up, ulr), left[r]);                        \
        left[r] = nv; ulr = diag; up = nv;                                     \
      }                                                                        \
      bot[k] = up;                                                             \
      u[k] = shr1(uba_s[k], up);                                               \
      ul = uin;                                                                \
    }                                                                          \
    ul_top = ul;                                                               \
    /* re-issue this slot for tile sigma+4 (uniform SGPR base, padded alloc) */\
    {                                                                          \
      const unsigned short* tbs = tb + (size_t)(sigma + 4) * 4096;             \
      LOAD8(QS, tbs)                                                           \
    }                                                                          \
    if (sigma >= 63 && lane == 63) {                                           \
      const int c63 = sigma - 63;                                              \
      float* orp = &outring[c63 & 63][0];                                      \
      *(float2*)(orp + 0) = make_float2(bot[0], bot[1]);                       \
      *(float2*)(orp + 2) = make_float2(bot[2], bot[3]);                       \
      *(float2*)(orp + 4) = make_float2(bot[4], bot[5]);                       \
      *(float2*)(orp + 6) = make_float2(bot[6], bot[7]);                       \
      if ((S) == 6 && sigma >= 70) {                                           \
        CBAR();   /* once per group: order outring data before flag */         \
        RLX_LDS(&sh_out, c63 + 1);                                             \
      }                                                                        \
    }                                                                          \
  }

__global__ __launch_bounds__(128, 1)
__attribute__((amdgpu_waves_per_eu(1)))
void dtw_dp(const unsigned short* __restrict__ dist,
            float* __restrict__ brow,
            int* __restrict__ progress) {
  const int tid = threadIdx.x;
  const int lane = tid & 63;
  const int wid = tid >> 6;
  const int b = blockIdx.x;
  const int sb = b & 3;          // band index within its side

  __shared__ __align__(16) float ubuf[128];
  __shared__ __align__(16) float outring[64][KK];
  __shared__ int sh_out, sh_pubc, sh_ubc, sh_gdone;

  if (tid == 0) { sh_out = 0; sh_pubc = 0; sh_ubc = 0; sh_gdone = 0; }
  ubuf[tid] = HUGEV;
  __syncthreads();

  const unsigned short* tb = dist + (size_t)b * NSIGA * 4096;

  if (wid == 1) {
    // ================= aux wave: boundary-in + publish-out ==================
    int ubg = (sb > 0) ? 0 : 64;
    int pubg = 0;                          // ALL bands publish (combine needs 3,7)
    int out_c = 0, gdone_c = 0, idle = 0;
    while (ubg < 64 || pubg < 64) {
      bool did = false;
      if (ubg < 64) {
        if (gdone_c < ubg - 1) gdone_c = ACQ_LDS(&sh_gdone);
        if (gdone_c >= ubg - 1) {
          int pr = __hip_atomic_load(progress + b - 1, __ATOMIC_RELAXED,
                                     __HIP_MEMORY_SCOPE_AGENT);
          if (pr >= ubg + 1) {
            float v = __hip_atomic_load(brow + (size_t)(b - 1) * SS + 64 * ubg + lane,
                                        __ATOMIC_RELAXED, __HIP_MEMORY_SCOPE_AGENT);
            asm volatile("s_waitcnt vmcnt(0)" ::: "memory");
            ubuf[((ubg & 1) << 6) + lane] = v;
            CBAR();
            if (lane == 0) RLX_LDS(&sh_ubc, ubg + 1);
            ubg++; did = true;
          }
        }
      }
      if (pubg < 64) {
        if (out_c < 8 * (pubg + 1)) out_c = ACQ_LDS(&sh_out);
        if (out_c >= 8 * (pubg + 1)) {
          float v = outring[((pubg << 3) + (lane >> 3)) & 63][lane & 7];
          __hip_atomic_store(brow + (size_t)b * SS + 64 * pubg + lane, v,
                             __ATOMIC_RELAXED, __HIP_MEMORY_SCOPE_AGENT);
          asm volatile("s_waitcnt vmcnt(0)" ::: "memory");
          if (lane == 0) {
            __hip_atomic_store(progress + b, pubg + 1, __ATOMIC_RELAXED,
                               __HIP_MEMORY_SCOPE_AGENT);
            RLX_LDS(&sh_pubc, (pubg + 1) << 3);
          }
          pubg++; did = true;
        }
      }
      if (!did) {
        __builtin_amdgcn_s_sleep(2);
        if (++idle > SPIN_MAX) break;
      } else idle = 0;
    }
  } else {
    // ================= compute wave =================
    __builtin_amdgcn_s_setprio(1);
    float left[RR], u[KK], ul_top;
#pragma unroll
    for (int r = 0; r < RR; ++r) left[r] = HUGEV;
#pragma unroll
    for (int k = 0; k < KK; ++k) u[k] = HUGEV;
    ul_top = (sb == 0 && lane == 0) ? 0.f : HUGEV;   // origin seed per side

    int pubc = 0, ubc = 0;
    uint4 qA[8], qB[8], qC[8], qD[8];
    float4 UA[2], UB[2];

    const unsigned vo = (unsigned)lane * 16u;
    const unsigned vo2 = vo + 4096u;

    // prologue: issue tiles 0..3 into the 4-slot ring (32 loads in flight)
    { const unsigned short* tbs = tb;                    LOAD8(qA, tbs) }
    { const unsigned short* tbs = tb + (size_t)1 * 4096; LOAD8(qB, tbs) }
    { const unsigned short* tbs = tb + (size_t)2 * 4096; LOAD8(qC, tbs) }
    { const unsigned short* tbs = tb + (size_t)3 * 4096; LOAD8(qD, tbs) }

    for (int g = 0; g < NG; ++g) {
      const int ubase = (g & 1) << 6;
      if (sb > 0 && g < 64 && ubc < g + 1) {
        int _gd = 0;
        do { ubc = ACQ_LDS(&sh_ubc); } while (ubc < g + 1 && ++_gd < SPIN_MAX);
      }
      { // outring space for this group
        const int need = 8 * g - 119;
        if (need > 0 && pubc < need) {
          int _gd = 0;
          do { pubc = ACQ_LDS(&sh_pubc); } while (pubc < need && ++_gd < SPIN_MAX);
        }
      }
      { // group head: lane-0 u fix-up + UA preload for S=0
        float4 h0 = *(const float4*)&ubuf[ubase];
        float4 h1 = *(const float4*)&ubuf[ubase + 4];
        UA[0] = *(const float4*)&ubuf[ubase + 8];
        UA[1] = *(const float4*)&ubuf[ubase + 12];
        float hh[8] = {h0.x, h0.y, h0.z, h0.w, h1.x, h1.y, h1.z, h1.w};
#pragma unroll
        for (int k = 0; k < KK; ++k) u[k] = (lane == 0) ? hh[k] : u[k];
      }
      DPFENCE()
      DPSTEP(g, 0, qA, UA, UB)
      DPSTEP(g, 1, qB, UB, UA)
      DPFENCE()
      DPSTEP(g, 2, qC, UA, UB)
      DPSTEP(g, 3, qD, UB, UA)
      DPFENCE()
      DPSTEP(g, 4, qA, UA, UB)
      DPSTEP(g, 5, qB, UB, UA)
      DPFENCE()
      DPSTEP(g, 6, qC, UA, UB)
      DPSTEP(g, 7, qD, UB, UA)
      if (lane == 0) RLX_LDS(&sh_gdone, g + 1);
    }
    asm volatile("s_waitcnt vmcnt(0)" ::: "memory");
  }
}

// ---------------- combine: min_j ( F[2047][j] + min(B[2048][j], B[2048][j+1]) )
__global__ __launch_bounds__(256) void dtw_combine(const float* __restrict__ brow,
                                                   float* __restrict__ out) {
  const float* browF = brow + (size_t)3 * SS;
  const float* browB = brow + (size_t)7 * SS;
  __shared__ float red[256];
  const int t = threadIdx.x;
  float m = HUGEV;
  for (int j = t; j < SS; j += 256) {
    float b1 = browB[(SS - 1) - j];
    float b2 = (j < SS - 1) ? browB[(SS - 2) - j] : HUGEV;
    m = fminf(m, browF[j] + fminf(b1, b2));
  }
  red[t] = m;
  __syncthreads();
  for (int s = 128; s > 0; s >>= 1) {
    if (t < s) red[t] = fminf(red[t], red[t + s]);
    __syncthreads();
  }
  if (t == 0) out[0] = red[0];
}

extern "C" void kernel_launch(void* const* d_in, const int* in_sizes, int n_in,
                              void* d_out, int out_size, void* d_ws, size_t ws_size,
                              hipStream_t stream) {
  const float* ref = (const float*)d_in[0];
  const float* tgt = (const float*)d_in[1];
  float* out = (float*)d_out;
  char* ws = (char*)d_ws;
  unsigned short* dist = (unsigned short*)ws;       // skewed tiles (padded): 38.3 MB
  size_t off = (size_t)NBANDS * NSIGA * 4096 * 2;
  float* brow = (float*)(ws + off);      off += (size_t)64 * SS * 4;
  int* progress = (int*)(ws + off);      off += 1024;
  float* r2 = (float*)(ws + off);        off += (size_t)TT * 4;
  float* t2 = (float*)(ws + off);

  dtw_norms<<<(TT + SS) / 256, 256, 0, stream>>>(ref, tgt, r2, t2, progress);
  dtw_dist<<<dim3(SS / 64, TT / 64), 256, 0, stream>>>(ref, tgt, r2, t2, dist);
  dtw_dp<<<NBANDS, 128, 0, stream>>>(dist, brow, progress);
  dtw_combine<<<1, 256, 0, stream>>>(brow, out);
}